// Round 1
// baseline (2815.346 us; speedup 1.0000x reference)
//
#include <hip/hip_runtime.h>

// GRU autoregressive decoder: B=16384, T=60, I=32, H=128, steps=30, x0 = x[:,30,:]
// y_t = h_t @ Wout^T + bout feeds back as x_{t+1}.
// Layout: 256 blocks x 256 threads; lane (0..63) = batch row within block,
// wave (0..3) owns 32 of the 128 hidden units and 8 of the 32 outputs.
// h[128], x[32] in VGPRs; weights streamed via wave-uniform s_load.

#define NB    16384
#define TT    60
#define II    32
#define HH    128
#define NSTEP 30
#define SEQ0  30
#define BM    64
#define HPAD  132   // 128 + 4 (16B-aligned rows, breaks pow2 bank stride)
#define XPAD  36    // 32 + 4

__device__ __forceinline__ float fast_sigmoid(float a) {
    return 1.0f / (1.0f + __expf(-a));
}
__device__ __forceinline__ float fast_tanh(float a) {
    // 1 - 2/(1+exp(2a)); saturates correctly at +-1 for large |a|
    return 1.0f - 2.0f / (1.0f + __expf(2.0f * a));
}

__global__ __launch_bounds__(256, 1)
void gru_decoder_kernel(const float* __restrict__ x,
                        const float* __restrict__ h0,
                        const float* __restrict__ Wih,
                        const float* __restrict__ Whh,
                        const float* __restrict__ bih,
                        const float* __restrict__ bhh,
                        const float* __restrict__ Wout,
                        const float* __restrict__ bout,
                        float* __restrict__ out)
{
    __shared__ float sh[BM * HPAD];  // h exchange (33.8 KB)
    __shared__ float sx[BM * XPAD];  // x/y exchange (9.2 KB)

    const int tid  = threadIdx.x;
    const int lane = tid & 63;
    const int wave = __builtin_amdgcn_readfirstlane(tid >> 6); // force wave-uniform
    const int row  = blockIdx.x * BM + lane;

    const int jbase = wave * (HH / 4);  // 32 hidden units per wave
    const int ibase = wave * (II / 4);  // 8 outputs per wave

    float h[HH];
    float xv[II];

    // ---- load h0[row, :] into registers (const-indexed -> VGPRs) ----
    {
        const float4* p = (const float4*)(h0 + (size_t)row * HH);
        #pragma unroll
        for (int k = 0; k < HH / 4; ++k) {
            float4 v = p[k];
            h[4 * k + 0] = v.x; h[4 * k + 1] = v.y;
            h[4 * k + 2] = v.z; h[4 * k + 3] = v.w;
        }
    }
    // ---- load x0 = x[row, 30, :] ----
    {
        const float4* p = (const float4*)(x + ((size_t)row * TT + SEQ0) * II);
        #pragma unroll
        for (int k = 0; k < II / 4; ++k) {
            float4 v = p[k];
            xv[4 * k + 0] = v.x; xv[4 * k + 1] = v.y;
            xv[4 * k + 2] = v.z; xv[4 * k + 3] = v.w;
        }
    }
    // Seed this lane's own j-slice of old-h in LDS (read back as h[j] in the
    // blend, avoiding a runtime index into the register array). Same-thread
    // RAW on LDS needs no barrier.
    {
        const float* hrow = h0 + (size_t)row * HH + jbase;
        #pragma unroll
        for (int jj = 0; jj < HH / 4; ++jj)
            sh[lane * HPAD + jbase + jj] = hrow[jj];
    }

    for (int s = 0; s < NSTEP; ++s) {
        // ---- GRU cell: h_new[j] for this wave's 32 j's ----
        for (int jj = 0; jj < HH / 4; ++jj) {
            const int j = jbase + jj;                 // wave-uniform
            const float* wr = Whh + (size_t)j * HH;
            const float* wz = Whh + (size_t)(HH + j) * HH;
            const float* wn = Whh + (size_t)(2 * HH + j) * HH;
            float gr = bhh[j];
            float gz = bhh[HH + j];
            float gn = bhh[2 * HH + j];
            #pragma unroll
            for (int k = 0; k < HH; ++k) {            // 3 indep FMA chains
                gr = fmaf(wr[k], h[k], gr);
                gz = fmaf(wz[k], h[k], gz);
                gn = fmaf(wn[k], h[k], gn);
            }
            const float* ur = Wih + (size_t)j * II;
            const float* uz = Wih + (size_t)(HH + j) * II;
            const float* un = Wih + (size_t)(2 * HH + j) * II;
            float ir = bih[j];
            float iz = bih[HH + j];
            float nn = bih[2 * HH + j];
            #pragma unroll
            for (int k = 0; k < II; ++k) {
                ir = fmaf(ur[k], xv[k], ir);
                iz = fmaf(uz[k], xv[k], iz);
                nn = fmaf(un[k], xv[k], nn);
            }
            const float r = fast_sigmoid(ir + gr);
            const float z = fast_sigmoid(iz + gz);
            const float n = fast_tanh(nn + r * gn);
            const float hold = sh[lane * HPAD + j];   // old h[j] (own slot)
            sh[lane * HPAD + j] = (1.0f - z) * n + z * hold;
        }
        __syncthreads();  // (a) h_new visible; also guards prev-iter sx reads

        // ---- reload full h_new into registers ----
        {
            const float4* p = (const float4*)&sh[lane * HPAD];
            #pragma unroll
            for (int k = 0; k < HH / 4; ++k) {
                float4 v = p[k];
                h[4 * k + 0] = v.x; h[4 * k + 1] = v.y;
                h[4 * k + 2] = v.z; h[4 * k + 3] = v.w;
            }
        }

        // ---- y[i] = h_new . Wout[i] + bout[i], 8 i's per wave ----
        float y0, y1, y2, y3, y4, y5, y6, y7;
        {
            float yv[II / 4];
            #pragma unroll
            for (int ii = 0; ii < II / 4; ++ii) {
                const int i = ibase + ii;             // wave-uniform
                const float* wo = Wout + (size_t)i * HH;
                float acc = bout[i];
                #pragma unroll
                for (int k = 0; k < HH; ++k) acc = fmaf(wo[k], h[k], acc);
                yv[ii] = acc;
            }
            y0 = yv[0]; y1 = yv[1]; y2 = yv[2]; y3 = yv[3];
            y4 = yv[4]; y5 = yv[5]; y6 = yv[6]; y7 = yv[7];
        }

        // ---- store y to out[row, s, ibase..ibase+8) ----
        {
            float4* po = (float4*)(out + ((size_t)row * NSTEP + s) * II + ibase);
            po[0] = make_float4(y0, y1, y2, y3);
            po[1] = make_float4(y4, y5, y6, y7);
        }

        // ---- y becomes next x ----
        sx[lane * XPAD + ibase + 0] = y0;
        sx[lane * XPAD + ibase + 1] = y1;
        sx[lane * XPAD + ibase + 2] = y2;
        sx[lane * XPAD + ibase + 3] = y3;
        sx[lane * XPAD + ibase + 4] = y4;
        sx[lane * XPAD + ibase + 5] = y5;
        sx[lane * XPAD + ibase + 6] = y6;
        sx[lane * XPAD + ibase + 7] = y7;
        __syncthreads();  // (b) sx visible; also guards sh reads vs next write
        {
            const float4* p = (const float4*)&sx[lane * XPAD];
            #pragma unroll
            for (int k = 0; k < II / 4; ++k) {
                float4 v = p[k];
                xv[4 * k + 0] = v.x; xv[4 * k + 1] = v.y;
                xv[4 * k + 2] = v.z; xv[4 * k + 3] = v.w;
            }
        }
    }
}

extern "C" void kernel_launch(void* const* d_in, const int* in_sizes, int n_in,
                              void* d_out, int out_size, void* d_ws, size_t ws_size,
                              hipStream_t stream) {
    (void)in_sizes; (void)n_in; (void)out_size; (void)d_ws; (void)ws_size;
    const float* x    = (const float*)d_in[0];
    const float* h0   = (const float*)d_in[1];
    const float* Wih  = (const float*)d_in[2];
    const float* Whh  = (const float*)d_in[3];
    const float* bih  = (const float*)d_in[4];
    const float* bhh  = (const float*)d_in[5];
    const float* Wout = (const float*)d_in[6];
    const float* bout = (const float*)d_in[7];
    float* out = (float*)d_out;

    dim3 grid(NB / BM);   // 256 blocks -> 1 per CU
    dim3 block(256);
    gru_decoder_kernel<<<grid, block, 0, stream>>>(x, h0, Wih, Whh, bih, bhh,
                                                   Wout, bout, out);
}

// Round 2
// 340.824 us; speedup vs baseline: 8.2604x; 8.2604x over previous
//
#include <hip/hip_runtime.h>

// GRU autoregressive decoder, bf16-MFMA persistent-weight version.
// B=16384, I=32, H=128, 30 steps, x0 = x[:,30,:], y feeds back as x.
//
// 256 blocks x 256 threads (1 block/CU). Block owns 64 batch rows.
// Wave w owns hidden units j in [32w, 32w+32) -> its gate weight columns as
// persistent MFMA B-fragments in VGPRs (~152 VGPRs). h-state is lane-private
// fp32 registers (D-layout slot of unit j maps to the same lane every step).
// bf16 h/x copies go through LDS only for the A-operand layout transform.
//
// GEMM1 per step: G[64x384] = [h|x][64x160] @ W'^T, K fused for r/z gates;
// n-gate keeps separate h-part (K=128, +bhh) and x-part (K=32, +bih) accs
// because n = tanh(i_n + r*h_n). Then y[64x32] = h'[64x128] @ Wout^T + bout.

#define NB    16384
#define TT    60
#define II    32
#define HH    128
#define NSTEP 30
#define SEQ0  30
#define BM    64
#define HBS   136   // bf16 h-row stride (elems): 272B rows, 16B-aligned, 2-way-free banks
#define XBS   40    // bf16 x-row stride: 80B rows

typedef __attribute__((ext_vector_type(8))) short bf16x8;
typedef __attribute__((ext_vector_type(4))) float f32x4;

#define MFMA(a, b, c) __builtin_amdgcn_mfma_f32_16x16x32_bf16((a), (b), (c), 0, 0, 0)

__device__ __forceinline__ short f2bf(float x) {  // RNE fp32->bf16
    unsigned u = __float_as_uint(x);
    u += 0x7FFFu + ((u >> 16) & 1u);
    return (short)(u >> 16);
}
__device__ __forceinline__ bf16x8 ldw8(const float* p) {  // 8 fp32 -> bf16x8
    float4 a = *(const float4*)p;
    float4 b = *(const float4*)(p + 4);
    bf16x8 f;
    f[0] = f2bf(a.x); f[1] = f2bf(a.y); f[2] = f2bf(a.z); f[3] = f2bf(a.w);
    f[4] = f2bf(b.x); f[5] = f2bf(b.y); f[6] = f2bf(b.z); f[7] = f2bf(b.w);
    return f;
}
__device__ __forceinline__ float sigm(float a)  { return 1.0f / (1.0f + __expf(-a)); }
__device__ __forceinline__ float tanhf_(float a){ return 1.0f - 2.0f / (1.0f + __expf(2.0f * a)); }

__global__ __launch_bounds__(256, 1)
void gru_mfma_kernel(const float* __restrict__ x,
                     const float* __restrict__ h0,
                     const float* __restrict__ Wih,
                     const float* __restrict__ Whh,
                     const float* __restrict__ bih,
                     const float* __restrict__ bhh,
                     const float* __restrict__ Wout,
                     const float* __restrict__ bout,
                     float* __restrict__ out)
{
    __shared__ short shb[2][BM * HBS];  // bf16 h, double-buffered (34.8 KB)
    __shared__ short sxb[BM * XBS];     // bf16 x/y feedback (5.1 KB)

    const int tid    = threadIdx.x;
    const int lane   = tid & 63;
    const int wave   = __builtin_amdgcn_readfirstlane(tid >> 6);
    const int n16    = lane & 15;   // MFMA col / A-row index
    const int quad   = lane >> 4;   // MFMA k-group / D-row group
    const int rowblk = blockIdx.x * BM;

    // ---- persistent weight B-fragments (lane n16 holds W'[col][k..k+7]) ----
    bf16x8 Br[2][5], Bz[2][5], Bnh[2][4], Bnx[2], Bo[2][4];
    float  b_r[2], b_z[2], b_nh[2], b_nx[2], b_o[2];
    #pragma unroll
    for (int u = 0; u < 2; ++u) {
        const int j = wave * 32 + u * 16 + n16;   // hidden unit (gate col)
        const float* wr = Whh + (size_t)j * HH;
        const float* wz = Whh + (size_t)(HH + j) * HH;
        const float* wn = Whh + (size_t)(2 * HH + j) * HH;
        #pragma unroll
        for (int kt = 0; kt < 4; ++kt) {
            Br[u][kt]  = ldw8(wr + kt * 32 + quad * 8);
            Bz[u][kt]  = ldw8(wz + kt * 32 + quad * 8);
            Bnh[u][kt] = ldw8(wn + kt * 32 + quad * 8);
        }
        Br[u][4] = ldw8(Wih + (size_t)j * II + quad * 8);
        Bz[u][4] = ldw8(Wih + (size_t)(HH + j) * II + quad * 8);
        Bnx[u]   = ldw8(Wih + (size_t)(2 * HH + j) * II + quad * 8);
        b_r[u]  = bih[j] + bhh[j];
        b_z[u]  = bih[HH + j] + bhh[HH + j];
        b_nh[u] = bhh[2 * HH + j];
        b_nx[u] = bih[2 * HH + j];
    }
    #pragma unroll
    for (int nt = 0; nt < 2; ++nt) {
        const int i = nt * 16 + n16;
        #pragma unroll
        for (int kt = 0; kt < 4; ++kt)
            Bo[nt][kt] = ldw8(Wout + (size_t)i * HH + kt * 32 + quad * 8);
        b_o[nt] = bout[i];
    }

    // ---- lane-private fp32 h-state: slot (mt,u,reg) = h[row][col] with
    //      row = mt*16 + quad*4 + reg, col = wave*32 + u*16 + n16 ----
    float hst[4][2][4];
    #pragma unroll
    for (int mt = 0; mt < 4; ++mt)
        #pragma unroll
        for (int u = 0; u < 2; ++u) {
            const int col = wave * 32 + u * 16 + n16;
            #pragma unroll
            for (int reg = 0; reg < 4; ++reg) {
                const int row = rowblk + mt * 16 + quad * 4 + reg;
                hst[mt][u][reg] = h0[(size_t)row * HH + col];
            }
        }

    // ---- stage bf16 h0 and x0 into LDS (one-time, cooperative) ----
    {
        const int r  = tid >> 2;
        const int c0 = (tid & 3) * 32;
        const float* src = h0 + (size_t)(rowblk + r) * HH + c0;
        #pragma unroll
        for (int q = 0; q < 4; ++q)
            *(bf16x8*)&shb[0][r * HBS + c0 + q * 8] = ldw8(src + q * 8);
    }
    if (tid < BM) {
        const float* src = x + ((size_t)(rowblk + tid) * TT + SEQ0) * II;
        #pragma unroll
        for (int q = 0; q < 4; ++q)
            *(bf16x8*)&sxb[tid * XBS + q * 8] = ldw8(src + q * 8);
    }
    __syncthreads();

    int p = 0;
    for (int s = 0; s < NSTEP; ++s) {
        // ======== phase 1: gates + h update (wave w: all 64 rows x its 32 units)
        #pragma unroll
        for (int mt = 0; mt < 4; ++mt) {
            bf16x8 A[5];   // A[m=n16][k=quad*8+j], K-tiles: 4 from h, 1 from x
            #pragma unroll
            for (int kt = 0; kt < 4; ++kt)
                A[kt] = *(const bf16x8*)&shb[p][(mt * 16 + n16) * HBS + kt * 32 + quad * 8];
            A[4] = *(const bf16x8*)&sxb[(mt * 16 + n16) * XBS + quad * 8];

            f32x4 ar[2], az[2], anh[2], anx[2];
            #pragma unroll
            for (int u = 0; u < 2; ++u) {
                ar[u]  = (f32x4){b_r[u],  b_r[u],  b_r[u],  b_r[u]};
                az[u]  = (f32x4){b_z[u],  b_z[u],  b_z[u],  b_z[u]};
                anh[u] = (f32x4){b_nh[u], b_nh[u], b_nh[u], b_nh[u]};
                anx[u] = (f32x4){b_nx[u], b_nx[u], b_nx[u], b_nx[u]};
            }
            #pragma unroll
            for (int kt = 0; kt < 4; ++kt)         // 6 indep acc chains per kt
                #pragma unroll
                for (int u = 0; u < 2; ++u) {
                    ar[u]  = MFMA(A[kt], Br[u][kt],  ar[u]);
                    az[u]  = MFMA(A[kt], Bz[u][kt],  az[u]);
                    anh[u] = MFMA(A[kt], Bnh[u][kt], anh[u]);
                }
            #pragma unroll
            for (int u = 0; u < 2; ++u) {          // x-part (K-tile 4)
                ar[u]  = MFMA(A[4], Br[u][4], ar[u]);
                az[u]  = MFMA(A[4], Bz[u][4], az[u]);
                anx[u] = MFMA(A[4], Bnx[u],   anx[u]);
            }
            // gates: D-layout col = n16-col, row = quad*4+reg
            #pragma unroll
            for (int u = 0; u < 2; ++u) {
                const int colw = wave * 32 + u * 16 + n16;
                #pragma unroll
                for (int reg = 0; reg < 4; ++reg) {
                    const float r = sigm(ar[u][reg]);
                    const float z = sigm(az[u][reg]);
                    const float n = tanhf_(anx[u][reg] + r * anh[u][reg]);
                    const float hnew = n + z * (hst[mt][u][reg] - n);
                    hst[mt][u][reg] = hnew;
                    shb[1 - p][(mt * 16 + quad * 4 + reg) * HBS + colw] = f2bf(hnew);
                }
            }
        }
        __syncthreads();   // h' visible to all waves; phase-1 x reads done

        // ======== phase 2: y = h' @ Wout^T + bout (wave w: rows 16w..16w+15)
        {
            bf16x8 A2[4];
            #pragma unroll
            for (int kt = 0; kt < 4; ++kt)
                A2[kt] = *(const bf16x8*)&shb[1 - p][(wave * 16 + n16) * HBS + kt * 32 + quad * 8];
            f32x4 yo[2];
            yo[0] = (f32x4){b_o[0], b_o[0], b_o[0], b_o[0]};
            yo[1] = (f32x4){b_o[1], b_o[1], b_o[1], b_o[1]};
            #pragma unroll
            for (int kt = 0; kt < 4; ++kt) {
                yo[0] = MFMA(A2[kt], Bo[0][kt], yo[0]);
                yo[1] = MFMA(A2[kt], Bo[1][kt], yo[1]);
            }
            #pragma unroll
            for (int nt = 0; nt < 2; ++nt)
                #pragma unroll
                for (int reg = 0; reg < 4; ++reg) {
                    const int r_l = wave * 16 + quad * 4 + reg;
                    const float yv = yo[nt][reg];
                    out[(size_t)(rowblk + r_l) * (NSTEP * II) + s * II + nt * 16 + n16] = yv;
                    sxb[r_l * XBS + nt * 16 + n16] = f2bf(yv);  // y -> next x
                }
        }
        p ^= 1;
        __syncthreads();   // x/h-buf visible before next step's phase-1 reads
    }
}

extern "C" void kernel_launch(void* const* d_in, const int* in_sizes, int n_in,
                              void* d_out, int out_size, void* d_ws, size_t ws_size,
                              hipStream_t stream) {
    (void)in_sizes; (void)n_in; (void)out_size; (void)d_ws; (void)ws_size;
    const float* x    = (const float*)d_in[0];
    const float* h0   = (const float*)d_in[1];
    const float* Wih  = (const float*)d_in[2];
    const float* Whh  = (const float*)d_in[3];
    const float* bih  = (const float*)d_in[4];
    const float* bhh  = (const float*)d_in[5];
    const float* Wout = (const float*)d_in[6];
    const float* bout = (const float*)d_in[7];
    float* out = (float*)d_out;

    dim3 grid(NB / BM);   // 256 blocks, 1 per CU
    dim3 block(256);
    gru_mfma_kernel<<<grid, block, 0, stream>>>(x, h0, Wih, Whh, bih, bhh,
                                                Wout, bout, out);
}

// Round 3
// 336.397 us; speedup vs baseline: 8.3691x; 1.0132x over previous
//
#include <hip/hip_runtime.h>

// GRU autoregressive decoder, bf16-MFMA persistent-weight version, 2 blocks/CU.
// B=16384, I=32, H=128, 30 steps, x0 = x[:,30,:], y feeds back as x.
//
// 512 blocks x 256 threads (2 blocks/CU -> 2 waves/SIMD for latency overlap).
// Block owns 32 batch rows. Wave w owns hidden units [32w, 32w+32) -> gate
// weight columns live as persistent MFMA B-fragments in VGPRs. h-state is
// lane-private fp32 (D-layout slot of a unit maps to the same lane every
// step). bf16 h/x copies round-trip LDS only for the A-operand transform.
//
// GEMM1 per step: G[32x384] = [h|x][32x160] @ W'^T (K fused for r/z; n-gate
// keeps separate h/x accs since n = tanh(i_n + r*h_n)).
// GEMM2: y[32x32] = h'[32x128] @ Wout^T + bout; wave w computes the
// (w>>1, w&1) 16x16 tile, so it only holds its own Wout column-tile.

#define NB    16384
#define TT    60
#define II    32
#define HH    128
#define NSTEP 30
#define SEQ0  30
#define BM    32
#define HBS   136   // bf16 h-row stride (elems): 272B rows, 16B-aligned
#define XBS   40    // bf16 x-row stride: 80B rows

typedef __attribute__((ext_vector_type(8))) short bf16x8;
typedef __attribute__((ext_vector_type(4))) float f32x4;

#define MFMA(a, b, c) __builtin_amdgcn_mfma_f32_16x16x32_bf16((a), (b), (c), 0, 0, 0)

__device__ __forceinline__ short f2bf(float x) {  // RNE fp32->bf16
    unsigned u = __float_as_uint(x);
    u += 0x7FFFu + ((u >> 16) & 1u);
    return (short)(u >> 16);
}
__device__ __forceinline__ bf16x8 ldw8(const float* p) {  // 8 fp32 -> bf16x8
    float4 a = *(const float4*)p;
    float4 b = *(const float4*)(p + 4);
    bf16x8 f;
    f[0] = f2bf(a.x); f[1] = f2bf(a.y); f[2] = f2bf(a.z); f[3] = f2bf(a.w);
    f[4] = f2bf(b.x); f[5] = f2bf(b.y); f[6] = f2bf(b.z); f[7] = f2bf(b.w);
    return f;
}
__device__ __forceinline__ float sigm(float a)  { return 1.0f / (1.0f + __expf(-a)); }
__device__ __forceinline__ float tanhf_(float a){ return 1.0f - 2.0f / (1.0f + __expf(2.0f * a)); }

__global__ __launch_bounds__(256, 2)
void gru_mfma_kernel(const float* __restrict__ x,
                     const float* __restrict__ h0,
                     const float* __restrict__ Wih,
                     const float* __restrict__ Whh,
                     const float* __restrict__ bih,
                     const float* __restrict__ bhh,
                     const float* __restrict__ Wout,
                     const float* __restrict__ bout,
                     float* __restrict__ out)
{
    __shared__ short shb[2][BM * HBS];  // bf16 h, double-buffered (17.4 KB)
    __shared__ short sxb[BM * XBS];     // bf16 x/y feedback (2.5 KB)

    const int tid    = threadIdx.x;
    const int lane   = tid & 63;
    const int wave   = __builtin_amdgcn_readfirstlane(tid >> 6);
    const int n16    = lane & 15;   // MFMA col / A-row index
    const int quad   = lane >> 4;   // MFMA k-group / D-row group
    const int rowblk = blockIdx.x * BM;

    // ---- persistent gate-weight B-fragments (lane n16 holds W'[col][k..k+7])
    bf16x8 Br[2][5], Bz[2][5], Bnh[2][4], Bnx[2];
    float  b_r[2], b_z[2], b_nh[2], b_nx[2];
    #pragma unroll
    for (int u = 0; u < 2; ++u) {
        const int j = wave * 32 + u * 16 + n16;   // hidden unit (gate col)
        const float* wr = Whh + (size_t)j * HH;
        const float* wz = Whh + (size_t)(HH + j) * HH;
        const float* wn = Whh + (size_t)(2 * HH + j) * HH;
        #pragma unroll
        for (int kt = 0; kt < 4; ++kt) {
            Br[u][kt]  = ldw8(wr + kt * 32 + quad * 8);
            Bz[u][kt]  = ldw8(wz + kt * 32 + quad * 8);
            Bnh[u][kt] = ldw8(wn + kt * 32 + quad * 8);
        }
        Br[u][4] = ldw8(Wih + (size_t)j * II + quad * 8);
        Bz[u][4] = ldw8(Wih + (size_t)(HH + j) * II + quad * 8);
        Bnx[u]   = ldw8(Wih + (size_t)(2 * HH + j) * II + quad * 8);
        b_r[u]  = bih[j] + bhh[j];
        b_z[u]  = bih[HH + j] + bhh[HH + j];
        b_nh[u] = bhh[2 * HH + j];
        b_nx[u] = bih[2 * HH + j];
    }
    // ---- phase-2 tile assignment + this wave's Wout column-tile ----
    const int rowtile = wave >> 1;    // 0/1: which 16 rows of the 32
    const int coltile = wave & 1;     // 0/1: which 16 output cols
    bf16x8 Bo[4];
    float  b_o;
    {
        const int i = coltile * 16 + n16;
        #pragma unroll
        for (int kt = 0; kt < 4; ++kt)
            Bo[kt] = ldw8(Wout + (size_t)i * HH + kt * 32 + quad * 8);
        b_o = bout[i];
    }

    // ---- lane-private fp32 h-state: slot (mt,u,reg) = h[row][col],
    //      row = mt*16 + quad*4 + reg, col = wave*32 + u*16 + n16 ----
    float hst[2][2][4];
    #pragma unroll
    for (int mt = 0; mt < 2; ++mt)
        #pragma unroll
        for (int u = 0; u < 2; ++u) {
            const int col = wave * 32 + u * 16 + n16;
            #pragma unroll
            for (int reg = 0; reg < 4; ++reg) {
                const int row = rowblk + mt * 16 + quad * 4 + reg;
                hst[mt][u][reg] = h0[(size_t)row * HH + col];
            }
        }

    // ---- stage bf16 h0 and x0 into LDS (one-time, cooperative) ----
    {
        const int r  = tid >> 3;            // 32 rows, 8 threads/row
        const int c0 = (tid & 7) * 16;      // 16 cols each
        const float* src = h0 + (size_t)(rowblk + r) * HH + c0;
        *(bf16x8*)&shb[0][r * HBS + c0]     = ldw8(src);
        *(bf16x8*)&shb[0][r * HBS + c0 + 8] = ldw8(src + 8);
    }
    if (tid < BM) {
        const float* src = x + ((size_t)(rowblk + tid) * TT + SEQ0) * II;
        #pragma unroll
        for (int q = 0; q < 4; ++q)
            *(bf16x8*)&sxb[tid * XBS + q * 8] = ldw8(src + q * 8);
    }
    __syncthreads();

    int p = 0;
    for (int s = 0; s < NSTEP; ++s) {
        // ======== phase 1: gates + h update (wave w: all 32 rows x its 32 units)
        #pragma unroll
        for (int mt = 0; mt < 2; ++mt) {
            bf16x8 A[5];   // A[m=n16][k=quad*8+j]; K-tiles: 4 from h, 1 from x
            #pragma unroll
            for (int kt = 0; kt < 4; ++kt)
                A[kt] = *(const bf16x8*)&shb[p][(mt * 16 + n16) * HBS + kt * 32 + quad * 8];
            A[4] = *(const bf16x8*)&sxb[(mt * 16 + n16) * XBS + quad * 8];

            f32x4 ar[2], az[2], anh[2], anx[2];
            #pragma unroll
            for (int u = 0; u < 2; ++u) {
                ar[u]  = (f32x4){b_r[u],  b_r[u],  b_r[u],  b_r[u]};
                az[u]  = (f32x4){b_z[u],  b_z[u],  b_z[u],  b_z[u]};
                anh[u] = (f32x4){b_nh[u], b_nh[u], b_nh[u], b_nh[u]};
                anx[u] = (f32x4){b_nx[u], b_nx[u], b_nx[u], b_nx[u]};
            }
            #pragma unroll
            for (int kt = 0; kt < 4; ++kt)         // 6 indep acc chains per kt
                #pragma unroll
                for (int u = 0; u < 2; ++u) {
                    ar[u]  = MFMA(A[kt], Br[u][kt],  ar[u]);
                    az[u]  = MFMA(A[kt], Bz[u][kt],  az[u]);
                    anh[u] = MFMA(A[kt], Bnh[u][kt], anh[u]);
                }
            #pragma unroll
            for (int u = 0; u < 2; ++u) {          // x-part (K-tile 4)
                ar[u]  = MFMA(A[4], Br[u][4], ar[u]);
                az[u]  = MFMA(A[4], Bz[u][4], az[u]);
                anx[u] = MFMA(A[4], Bnx[u],   anx[u]);
            }
            // gates: D-layout col = n16-col, row = quad*4+reg
            #pragma unroll
            for (int u = 0; u < 2; ++u) {
                const int colw = wave * 32 + u * 16 + n16;
                #pragma unroll
                for (int reg = 0; reg < 4; ++reg) {
                    const float r = sigm(ar[u][reg]);
                    const float z = sigm(az[u][reg]);
                    const float n = tanhf_(anx[u][reg] + r * anh[u][reg]);
                    const float hnew = n + z * (hst[mt][u][reg] - n);
                    hst[mt][u][reg] = hnew;
                    shb[1 - p][(mt * 16 + quad * 4 + reg) * HBS + colw] = f2bf(hnew);
                }
            }
        }
        __syncthreads();   // h' visible to all waves; phase-1 x reads done

        // ======== phase 2: y = h' @ Wout^T + bout; wave w does one 16x16 tile
        {
            bf16x8 A2[4];
            #pragma unroll
            for (int kt = 0; kt < 4; ++kt)
                A2[kt] = *(const bf16x8*)&shb[1 - p][(rowtile * 16 + n16) * HBS + kt * 32 + quad * 8];
            f32x4 yo = (f32x4){b_o, b_o, b_o, b_o};
            #pragma unroll
            for (int kt = 0; kt < 4; ++kt)
                yo = MFMA(A2[kt], Bo[kt], yo);
            #pragma unroll
            for (int reg = 0; reg < 4; ++reg) {
                const int r_l = rowtile * 16 + quad * 4 + reg;
                const float yv = yo[reg];
                out[(size_t)(rowblk + r_l) * (NSTEP * II) + s * II + coltile * 16 + n16] = yv;
                sxb[r_l * XBS + coltile * 16 + n16] = f2bf(yv);  // y -> next x
            }
        }
        p ^= 1;
        __syncthreads();   // sxb/shb visible before next step's phase-1 reads
    }
}

extern "C" void kernel_launch(void* const* d_in, const int* in_sizes, int n_in,
                              void* d_out, int out_size, void* d_ws, size_t ws_size,
                              hipStream_t stream) {
    (void)in_sizes; (void)n_in; (void)out_size; (void)d_ws; (void)ws_size;
    const float* x    = (const float*)d_in[0];
    const float* h0   = (const float*)d_in[1];
    const float* Wih  = (const float*)d_in[2];
    const float* Whh  = (const float*)d_in[3];
    const float* bih  = (const float*)d_in[4];
    const float* bhh  = (const float*)d_in[5];
    const float* Wout = (const float*)d_in[6];
    const float* bout = (const float*)d_in[7];
    float* out = (float*)d_out;

    dim3 grid(NB / BM);   // 512 blocks -> 2 per CU
    dim3 block(256);
    gru_mfma_kernel<<<grid, block, 0, stream>>>(x, h0, Wih, Whh, bih, bhh,
                                                Wout, bout, out);
}

// Round 4
// 313.668 us; speedup vs baseline: 8.9756x; 1.0725x over previous
//
#include <hip/hip_runtime.h>

// GRU autoregressive decoder, bf16-MFMA persistent-weight, 8-wave blocks.
// B=16384, I=32, H=128, 30 steps, x0 = x[:,30,:], y feeds back as x.
//
// 256 blocks x 512 threads (1 block/CU, 8 waves = 2 waves/SIMD). Block owns
// 64 batch rows. Wave w owns hidden units [16w, 16w+16) -> its gate weight
// columns as persistent MFMA B-fragments (15 bf16x8 = 60 VGPR; total wave
// demand ~160 regs, fits the 256-reg 2-wave/SIMD budget with NO spill —
// round 3's 4-wave/32-unit split demanded ~280 and spilled 74 MB to scratch).
// h-state is lane-private fp32 (the D-layout slot of a hidden unit maps to
// the same lane every step). bf16 h/x copies round-trip LDS only for the
// A-operand layout transform.
//
// GEMM1 per step: G[64x384] = [h|x][64x160] @ W'^T (K fused for r/z; n-gate
// keeps separate h/x accumulators since n = tanh(i_n + r*h_n)).
// GEMM2: y[64x32] = h'[64x128] @ Wout^T + bout; wave w computes the
// (w>>1, w&1) 16x16 tile and holds only its own Wout column-tile.

#define NB    16384
#define TT    60
#define II    32
#define HH    128
#define NSTEP 30
#define SEQ0  30
#define BM    64
#define HBS   144   // bf16 h-row stride: 288B rows (72 dwords, 72%32=8 ->
                    // the 4 quads' scalar h'-writes hit disjoint bank groups)
#define XBS   40    // bf16 x-row stride: 80B rows

typedef __attribute__((ext_vector_type(8))) short bf16x8;
typedef __attribute__((ext_vector_type(4))) float f32x4;

#define MFMA(a, b, c) __builtin_amdgcn_mfma_f32_16x16x32_bf16((a), (b), (c), 0, 0, 0)

__device__ __forceinline__ short f2bf(float x) {  // RNE fp32->bf16
    unsigned u = __float_as_uint(x);
    u += 0x7FFFu + ((u >> 16) & 1u);
    return (short)(u >> 16);
}
__device__ __forceinline__ bf16x8 ldw8(const float* p) {  // 8 fp32 -> bf16x8
    float4 a = *(const float4*)p;
    float4 b = *(const float4*)(p + 4);
    bf16x8 f;
    f[0] = f2bf(a.x); f[1] = f2bf(a.y); f[2] = f2bf(a.z); f[3] = f2bf(a.w);
    f[4] = f2bf(b.x); f[5] = f2bf(b.y); f[6] = f2bf(b.z); f[7] = f2bf(b.w);
    return f;
}
__device__ __forceinline__ float sigm(float a)  { return 1.0f / (1.0f + __expf(-a)); }
__device__ __forceinline__ float tanhf_(float a){ return 1.0f - 2.0f / (1.0f + __expf(2.0f * a)); }

__global__ __launch_bounds__(512, 2)
void gru_mfma_kernel(const float* __restrict__ x,
                     const float* __restrict__ h0,
                     const float* __restrict__ Wih,
                     const float* __restrict__ Whh,
                     const float* __restrict__ bih,
                     const float* __restrict__ bhh,
                     const float* __restrict__ Wout,
                     const float* __restrict__ bout,
                     float* __restrict__ out)
{
    __shared__ short shb[2][BM * HBS];  // bf16 h, double-buffered (36.9 KB)
    __shared__ short sxb[BM * XBS];     // bf16 x/y feedback (5.1 KB)

    const int tid    = threadIdx.x;
    const int lane   = tid & 63;
    const int wave   = __builtin_amdgcn_readfirstlane(tid >> 6);  // 0..7
    const int n16    = lane & 15;   // MFMA col / A-row index
    const int quad   = lane >> 4;   // MFMA k-group / D-row group
    const int rowblk = blockIdx.x * BM;

    // ---- persistent gate-weight B-fragments: wave w owns units [16w,16w+16)
    //      lane n16 holds W'[col=16w+n16][k = kt*32 + quad*8 .. +8) ----
    bf16x8 Br[5], Bz[5], Bnh[4], Bnx;
    float  b_r, b_z, b_nh, b_nx;
    {
        const int j = wave * 16 + n16;            // hidden unit (gate col)
        const float* wr = Whh + (size_t)j * HH;
        const float* wz = Whh + (size_t)(HH + j) * HH;
        const float* wn = Whh + (size_t)(2 * HH + j) * HH;
        #pragma unroll
        for (int kt = 0; kt < 4; ++kt) {
            Br[kt]  = ldw8(wr + kt * 32 + quad * 8);
            Bz[kt]  = ldw8(wz + kt * 32 + quad * 8);
            Bnh[kt] = ldw8(wn + kt * 32 + quad * 8);
        }
        Br[4] = ldw8(Wih + (size_t)j * II + quad * 8);
        Bz[4] = ldw8(Wih + (size_t)(HH + j) * II + quad * 8);
        Bnx   = ldw8(Wih + (size_t)(2 * HH + j) * II + quad * 8);
        b_r  = bih[j] + bhh[j];
        b_z  = bih[HH + j] + bhh[HH + j];
        b_nh = bhh[2 * HH + j];
        b_nx = bih[2 * HH + j];
    }
    // ---- phase-2 tile assignment + this wave's Wout column-tile ----
    const int rowtile = wave >> 1;    // 0..3: which 16 rows of the 64
    const int coltile = wave & 1;     // 0/1:  which 16 output cols
    bf16x8 Bo[4];
    float  b_o;
    {
        const int i = coltile * 16 + n16;
        #pragma unroll
        for (int kt = 0; kt < 4; ++kt)
            Bo[kt] = ldw8(Wout + (size_t)i * HH + kt * 32 + quad * 8);
        b_o = bout[i];
    }

    // ---- lane-private fp32 h-state: slot (mt,reg) = h[row][col],
    //      row = mt*16 + quad*4 + reg, col = wave*16 + n16 ----
    float hst[4][4];
    {
        const int col = wave * 16 + n16;
        #pragma unroll
        for (int mt = 0; mt < 4; ++mt)
            #pragma unroll
            for (int reg = 0; reg < 4; ++reg)
                hst[mt][reg] = h0[(size_t)(rowblk + mt * 16 + quad * 4 + reg) * HH + col];
    }

    // ---- stage bf16 h0 and x0 into LDS (one-time, cooperative) ----
    {
        const int r  = tid >> 3;            // 64 rows, 8 threads/row
        const int c0 = (tid & 7) * 16;      // 16 cols each
        const float* src = h0 + (size_t)(rowblk + r) * HH + c0;
        *(bf16x8*)&shb[0][r * HBS + c0]     = ldw8(src);
        *(bf16x8*)&shb[0][r * HBS + c0 + 8] = ldw8(src + 8);
    }
    if (tid < 256) {
        const int r  = tid >> 2;            // 64 rows, 4 threads/row
        const int c0 = (tid & 3) * 8;
        const float* src = x + ((size_t)(rowblk + r) * TT + SEQ0) * II + c0;
        *(bf16x8*)&sxb[r * XBS + c0] = ldw8(src);
    }
    __syncthreads();

    int p = 0;
    for (int s = 0; s < NSTEP; ++s) {
        // ==== phase 1: gates + h update (wave w: all 64 rows x its 16 units)
        #pragma unroll
        for (int mt = 0; mt < 4; ++mt) {
            bf16x8 A[5];   // A[m=n16][k=quad*8+j]; K-tiles: 4 from h, 1 from x
            #pragma unroll
            for (int kt = 0; kt < 4; ++kt)
                A[kt] = *(const bf16x8*)&shb[p][(mt * 16 + n16) * HBS + kt * 32 + quad * 8];
            A[4] = *(const bf16x8*)&sxb[(mt * 16 + n16) * XBS + quad * 8];

            f32x4 ar  = (f32x4){b_r,  b_r,  b_r,  b_r};
            f32x4 az  = (f32x4){b_z,  b_z,  b_z,  b_z};
            f32x4 anh = (f32x4){b_nh, b_nh, b_nh, b_nh};
            f32x4 anx = (f32x4){b_nx, b_nx, b_nx, b_nx};
            #pragma unroll
            for (int kt = 0; kt < 4; ++kt) {       // 3 indep acc chains per kt
                ar  = MFMA(A[kt], Br[kt],  ar);
                az  = MFMA(A[kt], Bz[kt],  az);
                anh = MFMA(A[kt], Bnh[kt], anh);
            }
            ar  = MFMA(A[4], Br[4], ar);           // x-part (K-tile 4)
            az  = MFMA(A[4], Bz[4], az);
            anx = MFMA(A[4], Bnx,   anx);

            // gates: D-layout col = wave*16+n16, row = mt*16 + quad*4 + reg
            {
                const int colw = wave * 16 + n16;
                #pragma unroll
                for (int reg = 0; reg < 4; ++reg) {
                    const float r = sigm(ar[reg]);
                    const float z = sigm(az[reg]);
                    const float n = tanhf_(anx[reg] + r * anh[reg]);
                    const float hnew = n + z * (hst[mt][reg] - n);
                    hst[mt][reg] = hnew;
                    shb[1 - p][(mt * 16 + quad * 4 + reg) * HBS + colw] = f2bf(hnew);
                }
            }
        }
        __syncthreads();   // h' visible to all waves; phase-1 x reads done

        // ==== phase 2: y = h' @ Wout^T + bout; wave w does one 16x16 tile
        {
            bf16x8 A2[4];
            #pragma unroll
            for (int kt = 0; kt < 4; ++kt)
                A2[kt] = *(const bf16x8*)&shb[1 - p][(rowtile * 16 + n16) * HBS + kt * 32 + quad * 8];
            f32x4 yo = (f32x4){b_o, b_o, b_o, b_o};
            #pragma unroll
            for (int kt = 0; kt < 4; ++kt)
                yo = MFMA(A2[kt], Bo[kt], yo);
            #pragma unroll
            for (int reg = 0; reg < 4; ++reg) {
                const int r_l = rowtile * 16 + quad * 4 + reg;
                const float yv = yo[reg];
                out[(size_t)(rowblk + r_l) * (NSTEP * II) + s * II + coltile * 16 + n16] = yv;
                sxb[r_l * XBS + coltile * 16 + n16] = f2bf(yv);  // y -> next x
            }
        }
        p ^= 1;
        __syncthreads();   // sxb/shb visible before next step's phase-1 reads
    }
}

extern "C" void kernel_launch(void* const* d_in, const int* in_sizes, int n_in,
                              void* d_out, int out_size, void* d_ws, size_t ws_size,
                              hipStream_t stream) {
    (void)in_sizes; (void)n_in; (void)out_size; (void)d_ws; (void)ws_size;
    const float* x    = (const float*)d_in[0];
    const float* h0   = (const float*)d_in[1];
    const float* Wih  = (const float*)d_in[2];
    const float* Whh  = (const float*)d_in[3];
    const float* bih  = (const float*)d_in[4];
    const float* bhh  = (const float*)d_in[5];
    const float* Wout = (const float*)d_in[6];
    const float* bout = (const float*)d_in[7];
    float* out = (float*)d_out;

    dim3 grid(NB / BM);   // 256 blocks -> 1 per CU (8 waves = 2 waves/SIMD)
    dim3 block(512);
    gru_mfma_kernel<<<grid, block, 0, stream>>>(x, h0, Wih, Whh, bih, bhh,
                                                Wout, bout, out);
}